// Round 8
// baseline (128.419 us; speedup 1.0000x reference)
//
#include <hip/hip_runtime.h>

// CumulativeFlattenedLinear: per-64-timestep-window projection (C=16 -> O=16,
// per-s weight slice, first ND=16 slots zero) + causal cumsum in window + bias.
//
// v8: NO LDS, NO BARRIERS (max contrast vs v5-v7, which were all ~31-33 us).
//  - 512-thr block = 8 independent waves over one 4-window slab (256 t).
//    Wave w owns o-pair (w, w+8): w0[16]+w1[16] = 32 long-lived regs (the
//    proven-resident scale; >32 spills -- R2/R3/R4 evidence).
//  - x straight from global: per window, 16 coalesced dword loads (one per c),
//    issued together and asm-pinned so the compiler can't sink them into the
//    FMA chain (R2's failure: serialized load latency). All 8 waves read the
//    same 16 KB slab -> 7/8 L1 hits. No transpose needed: load c gives lane i
//    x[c][t0+i], so each lane accumulates its t's dot-product directly.
//  - Output via nontemporal stores: out is write-once, never re-read ->
//    don't evict x from L2/L3 (x 64 MiB fits L3 256 MiB -> steady-state
//    FETCH should collapse).
//  - launch_bounds(512,6): 24 waves/CU target, VGPR cap 85 (est ~75).

#define CC 16
#define TT 131072
#define OO 16
#define NK 48
#define ND 16
#define GG 2048
#define WPS 4            // windows per slab (block)

// 64-lane inclusive prefix sum via DPP (verified R1).
#define SCAN_STEP(CTRL, RMASK)                                                  \
  {                                                                             \
    int t_ = __builtin_amdgcn_update_dpp(0, __float_as_int(v), (CTRL), (RMASK), \
                                         0xf, true);                            \
    v += __int_as_float(t_);                                                    \
  }

__device__ __forceinline__ float wave_scan64(float v) {
  SCAN_STEP(0x111, 0xf)  // row_shr:1
  SCAN_STEP(0x112, 0xf)  // row_shr:2
  SCAN_STEP(0x114, 0xf)  // row_shr:4
  SCAN_STEP(0x118, 0xf)  // row_shr:8
  SCAN_STEP(0x142, 0xa)  // row_bcast15
  SCAN_STEP(0x143, 0xc)  // row_bcast31
  return v;
}

__global__ __launch_bounds__(512, 6) void cfl_kernel(
    const float* __restrict__ x, const float* __restrict__ weight,
    const float* __restrict__ bias, float* __restrict__ out) {
  const int tid = threadIdx.x;
  const int lane = tid & 63;
  const int wid = tid >> 6;        // 0..7 -> o-pair (wid, wid+8)

  const int slab = blockIdx.x;     // 0..4095, 256 t each; no b straddle
  const int b = slab >> 9;         // 512 slabs per batch row
  const int t0 = (slab & 511) * 256;

  // per-wave o-pair weight slices: 32 long-lived regs, loaded once, pinned
  const int o0 = wid, o1 = wid + 8;
  float w0[CC], w1[CC];
#pragma unroll
  for (int c = 0; c < CC; ++c) {
    float a = 0.f, bq = 0.f;
    if (lane >= ND) {
      a = weight[o0 * (CC * NK) + c * NK + (lane - ND)];
      bq = weight[o1 * (CC * NK) + c * NK + (lane - ND)];
    }
    asm volatile("" : "+v"(a), "+v"(bq));
    w0[c] = a;
    w1[c] = bq;
  }
  const float b0 = bias[o0];
  const float b1 = bias[o1];

  const float* xb = x + (size_t)b * CC * TT + t0;
  float* ob = out + (size_t)b * OO * TT + t0;

#pragma unroll
  for (int k = 0; k < WPS; ++k) {
    const int t = k * 64 + lane;

    // 16 coalesced x loads, issued en-masse (MLP=16), then pinned
    float xv[CC];
#pragma unroll
    for (int c = 0; c < CC; ++c) xv[c] = xb[(size_t)c * TT + t];
#pragma unroll
    for (int c = 0; c < CC; ++c) asm volatile("" : "+v"(xv[c]));

    float p0 = 0.f, p1 = 0.f;
#pragma unroll
    for (int c = 0; c < CC; ++c) {
      p0 = fmaf(xv[c], w0[c], p0);
      p1 = fmaf(xv[c], w1[c], p1);
    }

    const float cs0 = wave_scan64(p0) + b0;
    const float cs1 = wave_scan64(p1) + b1;
    __builtin_nontemporal_store(cs0, &ob[(size_t)o0 * TT + t]);
    __builtin_nontemporal_store(cs1, &ob[(size_t)o1 * TT + t]);
  }
}

extern "C" void kernel_launch(void* const* d_in, const int* in_sizes, int n_in,
                              void* d_out, int out_size, void* d_ws, size_t ws_size,
                              hipStream_t stream) {
  const float* x = (const float*)d_in[0];
  const float* weight = (const float*)d_in[1];
  const float* bias = (const float*)d_in[2];
  float* out = (float*)d_out;

  // 4096 slabs (4 windows each) x 8 waves (o-pairs) per block.
  cfl_kernel<<<4096, 512, 0, stream>>>(x, weight, bias, out);
}

// Round 9
// 33.781 us; speedup vs baseline: 3.8015x; 3.8015x over previous
//
#include <hip/hip_runtime.h>

// CumulativeFlattenedLinear: per-64-timestep-window projection (C=16 -> O=16,
// per-s weight slice, first ND=16 slots zero) + causal cumsum in window + bias.
//
// v9 = v5 (best, 31.2us) + XOR-swizzled LDS granule to kill the 8-way bank
// conflict on staging writes (audit: v5 wrote (c4*256+t)*4+(c&3); lanes t,t+8
// hit the same bank -> 2.94x LDS-write cost inside the barrier critical path;
// invisible in rocprof since R5 because harness fill kernels outrank us).
//  - slot in granule = (c&3) ^ ((t>>3)&3): staging-write banks = 4*(t%8)+perm
//    -> 32 distinct banks over 32 lanes (2 lanes/bank over wave64 = free).
//  - reads unchanged (ds_read_b128 per granule); the element permutation is
//    absorbed into the WEIGHT LOAD order: perm = (lane>>3)&3 is constant per
//    lane for all k (k*64 multiple of 32), so w0p[4c4+j] = w[.., 4c4+(j^perm)].
//    No dynamic register indexing, no runtime cost.
//  - everything else identical to v5: 256 thr, 4 windows/block, 4096 blocks,
//    wave owns o-pair per phase (32 long-lived weight regs -- the proven
//    residency cap), DPP wave scan, scalar coalesced stores.

#define CC 16
#define TT 131072
#define OO 16
#define NK 48
#define ND 16
#define WPB 4            // windows per block tile
#define GG 2048          // windows per batch row

// 64-lane inclusive prefix sum via DPP (verified R1).
#define SCAN_STEP(CTRL, RMASK)                                                  \
  {                                                                             \
    int t_ = __builtin_amdgcn_update_dpp(0, __float_as_int(v), (CTRL), (RMASK), \
                                         0xf, true);                            \
    v += __int_as_float(t_);                                                    \
  }

__device__ __forceinline__ float wave_scan64(float v) {
  SCAN_STEP(0x111, 0xf)  // row_shr:1
  SCAN_STEP(0x112, 0xf)  // row_shr:2
  SCAN_STEP(0x114, 0xf)  // row_shr:4
  SCAN_STEP(0x118, 0xf)  // row_shr:8
  SCAN_STEP(0x142, 0xa)  // row_bcast15
  SCAN_STEP(0x143, 0xc)  // row_bcast31
  return v;
}

__global__ __launch_bounds__(256, 4) void cfl_kernel(
    const float* __restrict__ x, const float* __restrict__ weight,
    const float* __restrict__ bias, float* __restrict__ out) {
  // granule-major tile: [c4:4][t:256][4 slots], slot = (c&3)^((t>>3)&3). 16 KiB
  __shared__ __attribute__((aligned(16))) float tile[4 * 256 * 4];

  const int tid = threadIdx.x;
  const int lane = tid & 63;
  const int wid = tid >> 6;

  const int n0 = blockIdx.x * WPB;      // first window (b*GG + g)
  const int b = n0 >> 11;               // / GG
  const int t0 = (n0 & (GG - 1)) * 64;  // t offset within the batch row

  // ---- stage x tile: coalesced dword loads, CONFLICT-FREE swizzled writes
  const float* xb = x + (size_t)b * CC * TT + t0;
  {
    const int sw = (tid >> 3) & 3;  // write-side swizzle for t = tid
#pragma unroll
    for (int c = 0; c < CC; ++c) {
      float v = xb[(size_t)c * TT + tid];
      tile[(((c >> 2) * 256 + tid) << 2) + ((c & 3) ^ sw)] = v;
    }
  }
  __syncthreads();

  float* ob = out + (size_t)b * OO * TT + t0;
  const int perm = (lane >> 3) & 3;  // read-side slot->c permutation (const per lane)

#pragma unroll
  for (int p = 0; p < 2; ++p) {
    const int o0 = p * 4 + wid;  // this wave's o-pair: (o0, o0+8)

    // o-pair weight slices in SLOT order: w0p[4*c4+j] = w[o][4*c4+(j^perm)][lane-ND]
    float w0p[CC], w1p[CC];
#pragma unroll
    for (int c4 = 0; c4 < 4; ++c4) {
#pragma unroll
      for (int j = 0; j < 4; ++j) {
        const int ce = c4 * 4 + (j ^ perm);
        float a = 0.f, bq = 0.f;
        if (lane >= ND) {
          a = weight[o0 * (CC * NK) + ce * NK + (lane - ND)];
          bq = weight[(o0 + 8) * (CC * NK) + ce * NK + (lane - ND)];
        }
        w0p[c4 * 4 + j] = a;
        w1p[c4 * 4 + j] = bq;
      }
    }
    const float b0 = bias[o0];
    const float b1 = bias[o0 + 8];

#pragma unroll
    for (int k = 0; k < WPB; ++k) {
      const int t = k * 64 + lane;
      // 4x ds_read_b128, statically indexed
      const float4 xq0 = *(const float4*)&tile[(0 * 256 + t) << 2];
      const float4 xq1 = *(const float4*)&tile[(1 * 256 + t) << 2];
      const float4 xq2 = *(const float4*)&tile[(2 * 256 + t) << 2];
      const float4 xq3 = *(const float4*)&tile[(3 * 256 + t) << 2];

      float p0 = 0.f, p1 = 0.f;
      p0 = fmaf(xq0.x, w0p[0], p0);  p1 = fmaf(xq0.x, w1p[0], p1);
      p0 = fmaf(xq0.y, w0p[1], p0);  p1 = fmaf(xq0.y, w1p[1], p1);
      p0 = fmaf(xq0.z, w0p[2], p0);  p1 = fmaf(xq0.z, w1p[2], p1);
      p0 = fmaf(xq0.w, w0p[3], p0);  p1 = fmaf(xq0.w, w1p[3], p1);
      p0 = fmaf(xq1.x, w0p[4], p0);  p1 = fmaf(xq1.x, w1p[4], p1);
      p0 = fmaf(xq1.y, w0p[5], p0);  p1 = fmaf(xq1.y, w1p[5], p1);
      p0 = fmaf(xq1.z, w0p[6], p0);  p1 = fmaf(xq1.z, w1p[6], p1);
      p0 = fmaf(xq1.w, w0p[7], p0);  p1 = fmaf(xq1.w, w1p[7], p1);
      p0 = fmaf(xq2.x, w0p[8], p0);  p1 = fmaf(xq2.x, w1p[8], p1);
      p0 = fmaf(xq2.y, w0p[9], p0);  p1 = fmaf(xq2.y, w1p[9], p1);
      p0 = fmaf(xq2.z, w0p[10], p0); p1 = fmaf(xq2.z, w1p[10], p1);
      p0 = fmaf(xq2.w, w0p[11], p0); p1 = fmaf(xq2.w, w1p[11], p1);
      p0 = fmaf(xq3.x, w0p[12], p0); p1 = fmaf(xq3.x, w1p[12], p1);
      p0 = fmaf(xq3.y, w0p[13], p0); p1 = fmaf(xq3.y, w1p[13], p1);
      p0 = fmaf(xq3.z, w0p[14], p0); p1 = fmaf(xq3.z, w1p[14], p1);
      p0 = fmaf(xq3.w, w0p[15], p0); p1 = fmaf(xq3.w, w1p[15], p1);

      const float cs0 = wave_scan64(p0);
      const float cs1 = wave_scan64(p1);
      ob[(size_t)o0 * TT + t] = cs0 + b0;
      ob[(size_t)(o0 + 8) * TT + t] = cs1 + b1;
    }
  }
}

extern "C" void kernel_launch(void* const* d_in, const int* in_sizes, int n_in,
                              void* d_out, int out_size, void* d_ws, size_t ws_size,
                              hipStream_t stream) {
  const float* x = (const float*)d_in[0];
  const float* weight = (const float*)d_in[1];
  const float* bias = (const float*)d_in[2];
  float* out = (float*)d_out;

  // 16384 windows / 4 per block = 4096 blocks.
  cfl_kernel<<<4096, 256, 0, stream>>>(x, weight, bias, out);
}